// Round 9
// baseline (398.169 us; speedup 1.0000x reference)
//
#include <hip/hip_runtime.h>
#include <hip/hip_bf16.h>

// B=32, N=1024, D=768, H=12, d=64. Real tokens M=32768.
// Pad token handled analytically: ksum += 1.0 per component, kv/output unaffected.

typedef __bf16 bf16x8 __attribute__((ext_vector_type(8)));
typedef float f32x4 __attribute__((ext_vector_type(4)));

__device__ __forceinline__ ushort f2bf(float f) {
  union { float f; unsigned u; } x; x.f = f;
  unsigned r = x.u + 0x7fffu + ((x.u >> 16) & 1u);   // RNE
  return (ushort)(r >> 16);
}
__device__ __forceinline__ float bf2f(ushort h) {
  union { unsigned u; float f; } x; x.u = ((unsigned)h) << 16;
  return x.f;
}
__device__ __forceinline__ float bits2f(unsigned u) {
  union { unsigned u; float f; } x; x.u = u;
  return x.f;
}
__device__ __forceinline__ void gload_lds16(const void* g, void* lds) {
  __builtin_amdgcn_global_load_lds((const __attribute__((address_space(1))) void*)g,
                                   (__attribute__((address_space(3))) void*)lds, 16, 0, 0);
}
__device__ __forceinline__ bf16x8 ds_read128(const ushort* p) {
  bf16x8 r;
  asm volatile("ds_read_b128 %0, %1"
               : "=v"(r)
               : "v"((const __attribute__((address_space(3))) ushort*)p));
  return r;
}
// direct global->reg 16B load, asm (manual counted vmcnt; invisible to compiler waits)
__device__ __forceinline__ bf16x8 gload128(const ushort* p) {
  bf16x8 r;
  asm volatile("global_load_dwordx4 %0, %1, off"
               : "=v"(r)
               : "v"(p));
  return r;
}

// ---------------- fp32 -> bf16 elementwise (x4 vectorized) ----------------
__global__ __launch_bounds__(256) void cvt_f32_bf16(const float* __restrict__ in,
                                                    ushort* __restrict__ out, int n4) {
  int i = blockIdx.x * 256 + threadIdx.x;
  if (i >= n4) return;
  float4 v = reinterpret_cast<const float4*>(in)[i];
  ushort4 o;
  o.x = f2bf(v.x); o.y = f2bf(v.y); o.z = f2bf(v.z); o.w = f2bf(v.w);
  reinterpret_cast<ushort4*>(out)[i] = o;
}

// ---------------- transpose+convert: src[R][C] f32 -> dst[C][R] bf16 ----------------
__global__ __launch_bounds__(256) void transpose_cvt(const float* __restrict__ src,
                                                     ushort* __restrict__ dst, int R, int C) {
  __shared__ float tile[32][33];
  int bc = blockIdx.x * 32, br = blockIdx.y * 32;
  int tx = threadIdx.x & 31, ty = threadIdx.x >> 5;   // 32x8
  #pragma unroll
  for (int i = 0; i < 32; i += 8)
    tile[ty + i][tx] = src[(size_t)(br + ty + i) * C + (bc + tx)];
  __syncthreads();
  #pragma unroll
  for (int i = 0; i < 32; i += 8)
    dst[(size_t)(bc + ty + i) * R + (br + tx)] = f2bf(tile[tx][ty + i]);
}

// ==================== 64x256 multi-resident GEMM (B direct-to-reg) ====================
// C[M][N] = A[M][K] * Bt[N][K]^T, bf16 in, fp32 accum.
// 256 threads = 4 waves (all wm=0, wn=0..3); per-wave 64x64 out. BK=64, 2 phases/tile.
// A: LDS dbuf [2buf][2ks][64][32] = 16 KiB, XOR slot swizzle, 1 gload_lds/thread/phase.
//    p(ks0): stage k1(t+1)->nbuf; p(ks1): stage k0(t+2)->cbuf k0 (dead after ks0).
// B: 4x global_load_dwordx4 per phase direct to regs (Bt is L2-resident), double-
//    buffered X/Y one phase ahead. ~130 VGPR + 16 KiB -> 3 blocks/CU: cross-block
//    overlap keeps staging+MFMA pipes fed (the r7 gemm128 mechanism, without its
//    vmcnt(0) drain).
// Queue sim (per phase issue B4+A1): uniform vmcnt(6) retires exactly B_p at its
// consuming phase; A-stage confirmed 1+ phase before its read. Never drains.
// MODE 0: epilogue phi on cols<1536, store bf16.  MODE 1: +bias, store fp32.
template <int MODE>
__global__ __launch_bounds__(256, 3) void gemm64(const ushort* __restrict__ A,
                                                 const ushort* __restrict__ Bt,
                                                 void* __restrict__ C,
                                                 const float* __restrict__ bias,
                                                 int N, int K, int nbx, int cpx) {
  __shared__ ushort As[2][4096];     // [buf][ks*2048 + row*32 + slot*8]
  const int tid = threadIdx.x;
  const int lane = tid & 63;
  const int wn = tid >> 6;
  const int laneR = lane & 15, laneS = lane >> 4;

  // XCD-bijective swizzle (nwg % 8 == 0), bx-fastest within chunk
  const int bid = blockIdx.x;
  const int lin = (bid & 7) * cpx + (bid >> 3);
  const int by = lin / nbx, bx = lin - by * nbx;
  const int m0 = by * 64, n0 = bx * 256;
  const int NT = K >> 6;

  // A staging: thread -> row tid>>2 (64 rows), 16B slot tid&3 (inverse-swizzled src)
  const int sr = tid >> 2, ss = tid & 3;
  const int sslot = ss ^ ((sr >> 1) & 3);
  const ushort* Asrc = A + (size_t)(m0 + sr) * K + sslot * 8;
  const int ldst = tid * 8;          // ushort offset within a 2048-ushort ks-half

  // A frag reads: swizzled slot per-lane constant (row ≡ laneR mod 8)
  const int sprime = laneS ^ ((laneR >> 1) & 3);
  const int aoff = laneR * 32 + sprime * 8;        // + ks*2048 + i*512

  // B frag base: row (n-col), k-slice laneS*8; per j add j*16*K
  const ushort* Bb0 = Bt + (size_t)(n0 + wn * 64 + laneR) * K + laneS * 8;
  const size_t jstep = (size_t)16 * K;

  f32x4 acc[4][4] = {};
  bf16x8 afr[4], bfrX[4], bfrY[4];

  #define SBAR  __builtin_amdgcn_sched_barrier(0)
  #define MFMA16(AF, BF)                                                          \
    __builtin_amdgcn_s_setprio(1);                                                \
    _Pragma("unroll")                                                             \
    for (int ii = 0; ii < 4; ++ii)                                                \
      _Pragma("unroll")                                                           \
      for (int j = 0; j < 4; ++j)                                                 \
        acc[ii][j] =                                                              \
            __builtin_amdgcn_mfma_f32_16x16x32_bf16(AF[ii], BF[j], acc[ii][j], 0, 0, 0); \
    __builtin_amdgcn_s_setprio(0);

  // ---- prologue: A k0(0),k1(0),k0(1); B(t0,ks0)->X; full drain once ----
  gload_lds16(Asrc,      &As[0][0]    + ldst);
  gload_lds16(Asrc + 32, &As[0][2048] + ldst);
  gload_lds16(Asrc + 64, &As[1][0]    + ldst);
  #pragma unroll
  for (int j = 0; j < 4; ++j)
    bfrX[j] = gload128(Bb0 + (size_t)j * jstep);
  asm volatile("s_waitcnt vmcnt(0)" ::: "memory");
  SBAR;
  __builtin_amdgcn_s_barrier();
  SBAR;

  for (int t = 0; t < NT; ++t) {
    ushort* cb = &As[t & 1][0];
    ushort* nb = &As[(t & 1) ^ 1][0];
    const int t1 = (t + 1 < NT) ? t + 1 : t;   // clamped tail: dead stores/loads
    const int t2 = (t + 2 < NT) ? t + 2 : t;

    // ===== phase ks0: MFMA(afr, bfrX); load B(t,ks1)->Y; stage A k1(t+1)->nb =====
    #pragma unroll
    for (int i = 0; i < 4; ++i)
      afr[i] = ds_read128(cb + aoff + i * 512);
    #pragma unroll
    for (int j = 0; j < 4; ++j)
      bfrY[j] = gload128(Bb0 + (size_t)j * jstep + t * 64 + 32);
    gload_lds16(Asrc + t1 * 64 + 32, nb + 2048 + ldst);
    asm volatile("s_waitcnt vmcnt(6)" ::: "memory");
    SBAR;
    __builtin_amdgcn_s_barrier();
    asm volatile("s_waitcnt lgkmcnt(0)");
    SBAR;
    MFMA16(afr, bfrX);
    SBAR;
    __builtin_amdgcn_s_barrier();
    SBAR;

    // ===== phase ks1: MFMA(afr, bfrY); load B(t+1,ks0)->X; stage A k0(t+2)->cb =====
    #pragma unroll
    for (int i = 0; i < 4; ++i)
      afr[i] = ds_read128(cb + 2048 + aoff + i * 512);
    #pragma unroll
    for (int j = 0; j < 4; ++j)
      bfrX[j] = gload128(Bb0 + (size_t)j * jstep + t1 * 64);
    gload_lds16(Asrc + t2 * 64, cb + ldst);
    asm volatile("s_waitcnt vmcnt(6)" ::: "memory");
    SBAR;
    __builtin_amdgcn_s_barrier();
    asm volatile("s_waitcnt lgkmcnt(0)");
    SBAR;
    MFMA16(afr, bfrY);
    SBAR;
    __builtin_amdgcn_s_barrier();
    SBAR;
  }
  #undef MFMA16
  asm volatile("s_waitcnt vmcnt(0)" ::: "memory");    // drain dead tail loads

  // ---- epilogue: C/D layout col=lane&15, row=(lane>>4)*4+r ----
  #pragma unroll
  for (int i = 0; i < 4; ++i) {
    const int grow0 = m0 + i * 16 + (laneS << 2);
    #pragma unroll
    for (int j = 0; j < 4; ++j) {
      const int gcol = n0 + wn * 64 + j * 16 + laneR;
      #pragma unroll
      for (int r = 0; r < 4; ++r) {
        float v = acc[i][j][r];
        if (MODE == 0) {
          if (gcol < 1536) v = (v > 0.f) ? (v + 1.f) : __expf(v);   // phi on q,k
          reinterpret_cast<ushort*>(C)[(size_t)(grow0 + r) * N + gcol] = f2bf(v);
        } else {
          reinterpret_cast<float*>(C)[(size_t)(grow0 + r) * N + gcol] = v + bias[gcol];
        }
      }
    }
  }
}

// ==================== BMx256 2-phase GEMM (round-6; GEMM2, MFR=4) ========
template <int MODE, int MFR>
__global__ __launch_bounds__(512, 2) void gemm2ph(const ushort* __restrict__ A,
                                                  const ushort* __restrict__ Bt,
                                                  void* __restrict__ C,
                                                  const float* __restrict__ bias,
                                                  int N, int K, int nbx, int cpx) {
  constexpr int BM   = MFR * 32;
  constexpr int ALD  = MFR / 4;
  constexpr int AKS  = BM * 32;
  constexpr int BBASE = BM * 64;
  constexpr int BUFS = (BM + 256) * 64;
  extern __shared__ ushort lds[];
  const int tid = threadIdx.x;
  const int lane = tid & 63;
  const int wid = tid >> 6;
  const int wm = wid >> 2, wn = wid & 3;
  const int laneR = lane & 15, laneS = lane >> 4;

  const int bid = blockIdx.x;
  const int lin = (bid & 7) * cpx + (bid >> 3);
  const int by = lin / nbx, bx = lin - by * nbx;
  const int m0 = by * BM, n0 = bx * 256;
  const int NT = K >> 6;

  const int sr = tid >> 2, ss = tid & 3;
  const int sslot = ss ^ ((sr >> 1) & 3);
  const ushort* Asrc0 = A + (size_t)(m0 + sr) * K + sslot * 8;
  const ushort* Bsrc0 = Bt + (size_t)(n0 + sr) * K + sslot * 8;
  const size_t rowstep = (size_t)128 * K;
  const int ldst0 = tid * 8;

  const int sprime = laneS ^ ((laneR >> 1) & 3);
  const int aoff = (wm * (MFR * 16) + laneR) * 32 + sprime * 8;
  const int boff = BBASE + (wn * 64 + laneR) * 32 + sprime * 8;

  f32x4 acc[MFR][4] = {};
  bf16x8 afr[MFR], bfr[4];

  #define STAGE_K(KT, KS, DB)                                                     \
    { _Pragma("unroll")                                                           \
      for (int L = 0; L < ALD; ++L)                                               \
        gload_lds16(Asrc0 + (KT) * 64 + (KS) * 32 + (size_t)L * rowstep,          \
                    lds + (DB) + (KS) * AKS + L * 4096 + ldst0);                  \
      _Pragma("unroll")                                                           \
      for (int L = 0; L < 2; ++L)                                                 \
        gload_lds16(Bsrc0 + (KT) * 64 + (KS) * 32 + (size_t)L * rowstep,          \
                    lds + (DB) + BBASE + (KS) * 8192 + L * 4096 + ldst0); }
  #define VMCNT_WAIT                                                              \
    if constexpr (MFR == 8) asm volatile("s_waitcnt vmcnt(8)" ::: "memory");      \
    else                    asm volatile("s_waitcnt vmcnt(6)" ::: "memory");
  #define PHASE_SYNC                                                              \
    SBAR;                                                                         \
    __builtin_amdgcn_s_barrier();                                                 \
    asm volatile("s_waitcnt lgkmcnt(0)");                                         \
    SBAR;
  #define PHASE_END                                                               \
    SBAR;                                                                         \
    __builtin_amdgcn_s_barrier();                                                 \
    SBAR;
  #define MFMA_CL                                                                 \
    __builtin_amdgcn_s_setprio(1);                                                \
    _Pragma("unroll")                                                             \
    for (int ii = 0; ii < MFR; ++ii)                                              \
      _Pragma("unroll")                                                           \
      for (int j = 0; j < 4; ++j)                                                 \
        acc[ii][j] =                                                              \
            __builtin_amdgcn_mfma_f32_16x16x32_bf16(afr[ii], bfr[j], acc[ii][j], 0, 0, 0); \
    __builtin_amdgcn_s_setprio(0);

  STAGE_K(0, 0, 0);
  STAGE_K(0, 1, 0);
  STAGE_K(1, 0, BUFS);
  VMCNT_WAIT;
  SBAR;
  __builtin_amdgcn_s_barrier();
  SBAR;

  for (int t = 0; t < NT; ++t) {
    const int cb = (t & 1) * BUFS;
    const int nb = BUFS - cb;
    const int t1 = (t + 1 < NT) ? t + 1 : t;
    const int t2 = (t + 2 < NT) ? t + 2 : t;

    #pragma unroll
    for (int j = 0; j < 4; ++j) bfr[j] = ds_read128(lds + cb + boff + j * 512);
    #pragma unroll
    for (int ii = 0; ii < MFR; ++ii) afr[ii] = ds_read128(lds + cb + aoff + ii * 512);
    STAGE_K(t1, 1, nb);
    VMCNT_WAIT;
    PHASE_SYNC;
    MFMA_CL;
    PHASE_END;

    #pragma unroll
    for (int j = 0; j < 4; ++j) bfr[j] = ds_read128(lds + cb + 8192 + boff + j * 512);
    #pragma unroll
    for (int ii = 0; ii < MFR; ++ii) afr[ii] = ds_read128(lds + cb + AKS + aoff + ii * 512);
    STAGE_K(t2, 0, cb);
    VMCNT_WAIT;
    PHASE_SYNC;
    MFMA_CL;
    PHASE_END;
  }
  #undef STAGE_K
  #undef MFMA_CL
  #undef PHASE_SYNC
  #undef PHASE_END
  #undef VMCNT_WAIT
  asm volatile("s_waitcnt vmcnt(0)" ::: "memory");

  #pragma unroll
  for (int i = 0; i < MFR; ++i) {
    const int grow0 = m0 + wm * (MFR * 16) + i * 16 + (laneS << 2);
    #pragma unroll
    for (int j = 0; j < 4; ++j) {
      const int gcol = n0 + wn * 64 + j * 16 + laneR;
      #pragma unroll
      for (int r = 0; r < 4; ++r) {
        float v = acc[i][j][r];
        if (MODE == 0) {
          if (gcol < 1536) v = (v > 0.f) ? (v + 1.f) : __expf(v);
          reinterpret_cast<ushort*>(C)[(size_t)(grow0 + r) * N + gcol] = f2bf(v);
        } else {
          reinterpret_cast<float*>(C)[(size_t)(grow0 + r) * N + gcol] = v + bias[gcol];
        }
      }
    }
  }
}

// ---------------- kv partial: f32-in-LDS staging (convert once), stride-68 pad ------
__global__ __launch_bounds__(256) void kv_partial(const ushort* __restrict__ qkv,
                                                  float* __restrict__ kv_part,
                                                  float* __restrict__ ks_part) {
  const int blk = blockIdx.x;          // 384*4
  const int bh = blk >> 2, sp = blk & 3;
  const int b = bh / 12, h = bh % 12;
  const int tid = threadIdx.x;
  __shared__ float Ks[32 * 68];
  __shared__ float Vs[32 * 68];
  float acc[4][4] = {};                // [m][dq]
  float kacc[4] = {};
  const int dq0 = (tid & 15) * 4, mq0 = (tid >> 4) * 4;
  const int r = tid >> 3, o = (tid & 7) * 8;        // stage: row r, 8 cols from o
  for (int st = 0; st < 256; st += 32) {
    const size_t rowbase = (size_t)(b * 1024 + sp * 256 + st + r) * 2304 + h * 64 + o;
    int4 kraw = *reinterpret_cast<const int4*>(qkv + rowbase + 768);
    int4 vraw = *reinterpret_cast<const int4*>(qkv + rowbase + 1536);
    float kf[8], vf[8];
    {
      const unsigned* kw = reinterpret_cast<const unsigned*>(&kraw);
      const unsigned* vw = reinterpret_cast<const unsigned*>(&vraw);
      #pragma unroll
      for (int w = 0; w < 4; ++w) {
        kf[2 * w]     = bits2f(kw[w] << 16);
        kf[2 * w + 1] = bits2f(kw[w] & 0xffff0000u);
        vf[2 * w]     = bits2f(vw[w] << 16);
        vf[2 * w + 1] = bits2f(vw[w] & 0xffff0000u);
      }
    }
    __syncthreads();                   // prev-iter LDS reads done
    #pragma unroll
    for (int w = 0; w < 8; ++w) {
      Ks[r * 68 + o + w] = kf[w];
      Vs[r * 68 + o + w] = vf[w];
    }
    __syncthreads();                   // tile present
    #pragma unroll 8
    for (int s = 0; s < 32; ++s) {
      f32x4 kk = *reinterpret_cast<const f32x4*>(&Ks[s * 68 + dq0]);
      f32x4 vv = *reinterpret_cast<const f32x4*>(&Vs[s * 68 + mq0]);
      #pragma unroll
      for (int jm = 0; jm < 4; ++jm)
        #pragma unroll
        for (int id = 0; id < 4; ++id)
          acc[jm][id] += vv[jm] * kk[id];
      if (mq0 == 0) {
        #pragma unroll
        for (int id = 0; id < 4; ++id) kacc[id] += kk[id];
      }
    }
  }
  float* kvp = kv_part + ((size_t)sp * 384 + bh) * 4096;
  #pragma unroll
  for (int jm = 0; jm < 4; ++jm)
    #pragma unroll
    for (int id = 0; id < 4; ++id)
      kvp[(mq0 + jm) * 64 + dq0 + id] = acc[jm][id];
  if (mq0 == 0) {
    #pragma unroll
    for (int id = 0; id < 4; ++id)
      ks_part[((size_t)sp * 384 + bh) * 64 + dq0 + id] = kacc[id];
  }
}

// ---------------- reduce splits: kv -> bf16 [bh][m][dq], ksum += 1.0 (pad token) ----
__global__ __launch_bounds__(256) void kv_reduce(const float* __restrict__ kv_part,
                                                 const float* __restrict__ ks_part,
                                                 ushort* __restrict__ kv_bf,
                                                 float* __restrict__ ksum) {
  int i = blockIdx.x * 256 + threadIdx.x;
  if (i < 384 * 4096) {
    float s = 0.f;
    #pragma unroll
    for (int p = 0; p < 4; ++p) s += kv_part[(size_t)p * (384 * 4096) + i];
    kv_bf[i] = f2bf(s);
  }
  if (i < 384 * 64) {
    float s = 1.0f;    // phi(0)=1 contribution of the zero padding token
    #pragma unroll
    for (int p = 0; p < 4; ++p) s += ks_part[(size_t)p * (384 * 64) + i];
    ksum[i] = s;
  }
}

// ---------------- attention: out[t][h*64+m] = z[t] * sum_dq q[t][dq]*kv[dq][m] -------
__global__ __launch_bounds__(256) void attn_kernel(const ushort* __restrict__ qkv,
                                                   const ushort* __restrict__ kv_bf,
                                                   const float* __restrict__ ksum,
                                                   ushort* __restrict__ attn) {
  const int blk = blockIdx.x;          // 384*8
  const int bh = blk >> 3, tb = blk & 7;
  const int b = bh / 12, h = bh % 12;
  const int row0 = b * 1024 + tb * 128;
  __shared__ ushort Qs[128 * 64];
  __shared__ ushort KVs[64 * 64];      // [m][dq]
  __shared__ float zs[128];
  __shared__ float ks_lds[64];
  const int tid = threadIdx.x;
  const int lane = tid & 63, w = tid >> 6;
  #pragma unroll
  for (int j = 0; j < 4; ++j) {
    int c = j * 256 + tid;
    gload_lds16(qkv + (size_t)(row0 + (c >> 3)) * 2304 + h * 64 + (c & 7) * 8, &Qs[c * 8]);
  }
  #pragma unroll
  for (int j = 0; j < 2; ++j) {
    int c = j * 256 + tid;
    gload_lds16(kv_bf + (size_t)bh * 4096 + c * 8, &KVs[c * 8]);
  }
  if (tid < 64) ks_lds[tid] = ksum[bh * 64 + tid];
  asm volatile("s_waitcnt vmcnt(0)" ::: "memory");
  __syncthreads();
  if (tid < 128) {
    float d = 0.f;
    #pragma unroll 8
    for (int e = 0; e < 64; ++e) d += bf2f(Qs[tid * 64 + e]) * ks_lds[e];
    zs[tid] = 1.f / (d + 1e-6f);
  }
  __syncthreads();
  f32x4 acc[2][4] = {};
  #pragma unroll
  for (int ks = 0; ks < 2; ++ks) {
    bf16x8 a[2], bb[4];
    #pragma unroll
    for (int i = 0; i < 2; ++i)
      a[i] = *reinterpret_cast<const bf16x8*>(&Qs[(w * 32 + i * 16 + (lane & 15)) * 64 + ks * 32 + (lane >> 4) * 8]);
    #pragma unroll
    for (int j = 0; j < 4; ++j)
      bb[j] = *reinterpret_cast<const bf16x8*>(&KVs[(j * 16 + (lane & 15)) * 64 + ks * 32 + (lane >> 4) * 8]);
    #pragma unroll
    for (int i = 0; i < 2; ++i)
      #pragma unroll
      for (int j = 0; j < 4; ++j)
        acc[i][j] = __builtin_amdgcn_mfma_f32_16x16x32_bf16(a[i], bb[j], acc[i][j], 0, 0, 0);
  }
  #pragma unroll
  for (int i = 0; i < 2; ++i) {
    const int t0 = w * 32 + i * 16 + ((lane >> 4) << 2);
    #pragma unroll
    for (int j = 0; j < 4; ++j) {
      const int m = j * 16 + (lane & 15);
      #pragma unroll
      for (int r = 0; r < 4; ++r) {
        float v = acc[i][j][r] * zs[t0 + r];
        attn[(size_t)(row0 + t0 + r) * 768 + h * 64 + m] = f2bf(v);
      }
    }
  }
}

// ---------------- launch ----------------
extern "C" void kernel_launch(void* const* d_in, const int* in_sizes, int n_in,
                              void* d_out, int out_size, void* d_ws, size_t ws_size,
                              hipStream_t stream) {
  (void)in_sizes; (void)n_in; (void)out_size; (void)ws_size;
  const float* x    = (const float*)d_in[0];
  const float* Wqkv = (const float*)d_in[1];
  const float* Wout = (const float*)d_in[2];
  const float* bout = (const float*)d_in[3];
  float* out = (float*)d_out;
  char* ws = (char*)d_ws;

  // workspace layout (total ~210 MB); region 0 is reused by 3 time-disjoint buffers
  ushort* xbf    = (ushort*)(ws);               // 50,331,648 B : x bf16 [32768][768]
  ushort* wqkvT  = (ushort*)(ws + 50331648);    //  3,538,944 B : W_qkv^T bf16 [2304][768]
  ushort* woutT  = (ushort*)(ws + 53870592);    //  1,179,648 B : W_out^T bf16 [768][768]
  ushort* qkv    = (ushort*)(ws + 55050240);    // 150,994,944 B: phi(q)|phi(k)|v bf16 [32768][2304]
  float*  ksp    = (float*) (ws + 206045184);   //    393,216 B : ksum partials [4][384][64]
  ushort* kvbf   = (ushort*)(ws + 206438400);   //  3,145,728 B : kv bf16 [384][64m][64dq]
  float*  ksum   = (float*) (ws + 209584128);   //     98,304 B : ksum+1 [384][64]
  float*  kvpart = (float*)(ws);                // 25,165,824 B : overlays xbf (dead after gemm1)
  ushort* attn   = (ushort*)(ws);               // 50,331,648 B : overlays kvpart (dead after kv_reduce)

  static const int LDS2 = 98304;    // gemm2ph MFR=4: (128+256)*64*2*2
  hipFuncSetAttribute(reinterpret_cast<const void*>(&gemm2ph<1, 4>),
                      hipFuncAttributeMaxDynamicSharedMemorySize, LDS2);

  cvt_f32_bf16<<<24576, 256, 0, stream>>>(x, xbf, 6291456);
  transpose_cvt<<<dim3(72, 24), 256, 0, stream>>>(Wqkv, wqkvT, 768, 2304);
  transpose_cvt<<<dim3(24, 24), 256, 0, stream>>>(Wout, woutT, 768, 768);
  // GEMM1: 64x256 tiles -> grid 512x9 = 4608 (cpx=576), 3 blocks/CU
  gemm64<0><<<4608, 256, 0, stream>>>(xbf, wqkvT, qkv, nullptr, 2304, 768, 9, 576);
  kv_partial<<<1536, 256, 0, stream>>>(qkv, kvpart, ksp);
  kv_reduce<<<6144, 256, 0, stream>>>(kvpart, ksp, kvbf, ksum);
  attn_kernel<<<3072, 256, 0, stream>>>(qkv, kvbf, ksum, attn);
  // GEMM2: 128x256 tiles -> grid 256x3 = 768 (cpx=96), 3 exact generations
  gemm2ph<1, 4><<<768, 512, LDS2, stream>>>(attn, woutT, out, bout, 768, 768, 3, 96);
}

// Round 10
// 318.139 us; speedup vs baseline: 1.2516x; 1.2516x over previous
//
#include <hip/hip_runtime.h>
#include <hip/hip_bf16.h>

// B=32, N=1024, D=768, H=12, d=64. Real tokens M=32768.
// Pad token handled analytically: ksum += 1.0 per component, kv/output unaffected.

typedef __bf16 bf16x8 __attribute__((ext_vector_type(8)));
typedef float f32x4 __attribute__((ext_vector_type(4)));

__device__ __forceinline__ ushort f2bf(float f) {
  union { float f; unsigned u; } x; x.f = f;
  unsigned r = x.u + 0x7fffu + ((x.u >> 16) & 1u);   // RNE
  return (ushort)(r >> 16);
}
__device__ __forceinline__ float bf2f(ushort h) {
  union { unsigned u; float f; } x; x.u = ((unsigned)h) << 16;
  return x.f;
}
__device__ __forceinline__ float bits2f(unsigned u) {
  union { unsigned u; float f; } x; x.u = u;
  return x.f;
}
__device__ __forceinline__ void gload_lds16(const void* g, void* lds) {
  __builtin_amdgcn_global_load_lds((const __attribute__((address_space(1))) void*)g,
                                   (__attribute__((address_space(3))) void*)lds, 16, 0, 0);
}
__device__ __forceinline__ bf16x8 ds_read128(const ushort* p) {
  bf16x8 r;
  asm volatile("ds_read_b128 %0, %1"
               : "=v"(r)
               : "v"((const __attribute__((address_space(3))) ushort*)p));
  return r;
}
__device__ __forceinline__ void ds_write128(ushort* p, bf16x8 v) {
  asm volatile("ds_write_b128 %0, %1"
               :: "v"((__attribute__((address_space(3))) ushort*)p), "v"(v)
               : "memory");
}
// direct global->reg 16B load, asm (manual counted vmcnt)
__device__ __forceinline__ bf16x8 gload128(const ushort* p) {
  bf16x8 r;
  asm volatile("global_load_dwordx4 %0, %1, off"
               : "=v"(r)
               : "v"(p));
  return r;
}

// ---------------- fp32 -> bf16 elementwise (x4 vectorized) ----------------
__global__ __launch_bounds__(256) void cvt_f32_bf16(const float* __restrict__ in,
                                                    ushort* __restrict__ out, int n4) {
  int i = blockIdx.x * 256 + threadIdx.x;
  if (i >= n4) return;
  float4 v = reinterpret_cast<const float4*>(in)[i];
  ushort4 o;
  o.x = f2bf(v.x); o.y = f2bf(v.y); o.z = f2bf(v.z); o.w = f2bf(v.w);
  reinterpret_cast<ushort4*>(out)[i] = o;
}

// ---------------- transpose+convert: src[R][C] f32 -> dst[C][R] bf16 ----------------
__global__ __launch_bounds__(256) void transpose_cvt(const float* __restrict__ src,
                                                     ushort* __restrict__ dst, int R, int C) {
  __shared__ float tile[32][33];
  int bc = blockIdx.x * 32, br = blockIdx.y * 32;
  int tx = threadIdx.x & 31, ty = threadIdx.x >> 5;   // 32x8
  #pragma unroll
  for (int i = 0; i < 32; i += 8)
    tile[ty + i][tx] = src[(size_t)(br + ty + i) * C + (bc + tx)];
  __syncthreads();
  #pragma unroll
  for (int i = 0; i < 32; i += 8)
    dst[(size_t)(bc + ty + i) * R + (br + tx)] = f2bf(tile[tx][ty + i]);
}

// ==================== 256x256 4-phase GEMM, REG-STAGING (r4 skeleton) ====================
// Staging mechanism swapped: global_load_dwordx4 -> VGPR (issue at phase p) ->
// ds_write_b128 (phase p+1, after vmcnt(2)) into the same dead region r4 targeted.
// Writes are lgkmcnt(0)-drained before the mid-phase barrier that publishes them;
// every region is consumed >=2 barriers after publication (hazard map re-derived).
// Issue->write->read map per tile t:
//   p0: issue A(t1,ks1)->r0 ; write r3 = B(t+1,ks0) -> nbuf B-ks0
//   p1: issue B(t1,ks1)->r1 ; write r0 = A(t+1,ks1) -> nbuf A-ks1
//   p2: issue A(t2,ks0)->r2 ; write r1 = B(t+1,ks1) -> nbuf B-ks1
//   p3: issue B(t2,ks0)->r3 ; write r2 = A(t+2,ks0) -> cbuf A-ks0 (dead after p0 read)
// MODE 0: epilogue phi on cols<1536, store bf16.  MODE 1: +bias, store fp32.
template <int MODE>
__global__ __launch_bounds__(512, 2) void gemm256(const ushort* __restrict__ A,
                                                  const ushort* __restrict__ Bt,
                                                  void* __restrict__ C,
                                                  const float* __restrict__ bias,
                                                  int N, int K, int nbx, int cpx) {
  extern __shared__ ushort lds[];
  const int tid = threadIdx.x;
  const int lane = tid & 63;
  const int wid = tid >> 6;
  const int wm = wid >> 2, wn = wid & 3;
  const int laneR = lane & 15, laneS = lane >> 4;

  const int bid = blockIdx.x;
  const int lin = (bid & 7) * cpx + (bid >> 3);
  const int by = lin / nbx, bx = lin - by * nbx;
  const int m0 = by * 256, n0 = bx * 256;
  const int NT = K >> 6;

  const int sr = tid >> 2, ss = tid & 3;
  const int sslot = ss ^ ((sr >> 1) & 3);
  const ushort* Asrc0 = A + (size_t)(m0 + sr) * K + sslot * 8;
  const ushort* Bsrc0 = Bt + (size_t)(n0 + sr) * K + sslot * 8;
  const size_t rowstep = (size_t)128 * K;
  const int ldst0 = tid * 8;

  const int sprime = laneS ^ ((laneR >> 1) & 3);
  const int aoff = (wm * 128 + laneR) * 32 + sprime * 8;     // + ks*8192 + frag*512
  const int boff = 16384 + (wn * 64 + laneR) * 32 + sprime * 8;

  f32x4 acc[8][4] = {};
  bf16x8 afrX[4], afrY[4], bfrX[4], bfrY[4];
  bf16x8 r0a, r0b, r1a, r1b, r2a, r2b, r3a, r3b;

  #define SBAR  __builtin_amdgcn_sched_barrier(0)
  #define MFMA16(ACCBASE, AF, BF)                                                 \
    _Pragma("unroll")                                                             \
    for (int ii = 0; ii < 4; ++ii)                                                \
      _Pragma("unroll")                                                           \
      for (int j = 0; j < 4; ++j)                                                 \
        acc[(ACCBASE) + ii][j] =                                                  \
            __builtin_amdgcn_mfma_f32_16x16x32_bf16(AF[ii], BF[j], acc[(ACCBASE) + ii][j], 0, 0, 0);

  // ---- prologue: write tile0 (both ks) + tile1 A-ks0; leave B(1,ks0) in flight ----
  r0a = gload128(Asrc0);            r0b = gload128(Asrc0 + rowstep);
  r1a = gload128(Bsrc0);            r1b = gload128(Bsrc0 + rowstep);
  asm volatile("s_waitcnt vmcnt(0)" ::: "memory");
  ds_write128(lds + ldst0, r0a);            ds_write128(lds + 4096 + ldst0, r0b);
  ds_write128(lds + 16384 + ldst0, r1a);    ds_write128(lds + 16384 + 4096 + ldst0, r1b);
  r0a = gload128(Asrc0 + 32);       r0b = gload128(Asrc0 + 32 + rowstep);
  r1a = gload128(Bsrc0 + 32);       r1b = gload128(Bsrc0 + 32 + rowstep);
  asm volatile("s_waitcnt vmcnt(0)" ::: "memory");
  ds_write128(lds + 8192 + ldst0, r0a);     ds_write128(lds + 8192 + 4096 + ldst0, r0b);
  ds_write128(lds + 16384 + 8192 + ldst0, r1a);
  ds_write128(lds + 16384 + 8192 + 4096 + ldst0, r1b);
  r2a = gload128(Asrc0 + 64);       r2b = gload128(Asrc0 + 64 + rowstep);
  asm volatile("s_waitcnt vmcnt(0)" ::: "memory");
  ds_write128(lds + 32768 + ldst0, r2a);    ds_write128(lds + 32768 + 4096 + ldst0, r2b);
  r3a = gload128(Bsrc0 + 64);       r3b = gload128(Bsrc0 + 64 + rowstep);   // in flight
  asm volatile("s_waitcnt lgkmcnt(0)" ::: "memory");
  SBAR;
  __builtin_amdgcn_s_barrier();
  SBAR;
  #pragma unroll
  for (int j = 0; j < 4; ++j)
    bfrX[j] = *(const bf16x8*)(lds + boff + j * 512);
  #pragma unroll
  for (int ii = 0; ii < 4; ++ii)
    afrX[ii] = *(const bf16x8*)(lds + aoff + ii * 512);

  for (int t = 0; t < NT; ++t) {
    ushort* cbuf = lds + (t & 1) * 32768;
    ushort* nbuf = lds + ((t & 1) ^ 1) * 32768;
    const int t1 = (t + 1 < NT) ? t + 1 : t;   // clamped tail: dead loads/writes
    const int t2 = (t + 2 < NT) ? t + 2 : t;

    // ===== p0: MFMA(afrX,bfrX); prefetch afrY(cbuf k0 ih1); issue A(t1,ks1); write r3 =====
    #pragma unroll
    for (int ii = 0; ii < 4; ++ii)
      afrY[ii] = *(const bf16x8*)(cbuf + aoff + (4 + ii) * 512);
    r0a = gload128(Asrc0 + t1 * 64 + 32);
    r0b = gload128(Asrc0 + t1 * 64 + 32 + rowstep);
    asm volatile("s_waitcnt vmcnt(2)" ::: "memory");
    ds_write128(nbuf + 16384 + ldst0, r3a);                  // B ks0 (tile t+1)
    ds_write128(nbuf + 16384 + 4096 + ldst0, r3b);
    asm volatile("s_waitcnt lgkmcnt(0)" ::: "memory");
    SBAR;
    __builtin_amdgcn_s_barrier();
    SBAR;
    __builtin_amdgcn_s_setprio(1);
    MFMA16(0, afrX, bfrX);
    __builtin_amdgcn_s_setprio(0);
    SBAR;
    __builtin_amdgcn_s_barrier();
    SBAR;

    // ===== p1: MFMA(afrY,bfrX); prefetch bfrY,afrX(cbuf k1); issue B(t1,ks1); write r0 =====
    #pragma unroll
    for (int j = 0; j < 4; ++j)
      bfrY[j] = *(const bf16x8*)(cbuf + 8192 + boff + j * 512);
    #pragma unroll
    for (int ii = 0; ii < 4; ++ii)
      afrX[ii] = *(const bf16x8*)(cbuf + 8192 + aoff + ii * 512);
    r1a = gload128(Bsrc0 + t1 * 64 + 32);
    r1b = gload128(Bsrc0 + t1 * 64 + 32 + rowstep);
    asm volatile("s_waitcnt vmcnt(2)" ::: "memory");
    ds_write128(nbuf + 8192 + ldst0, r0a);                   // A ks1 (tile t+1)
    ds_write128(nbuf + 8192 + 4096 + ldst0, r0b);
    asm volatile("s_waitcnt lgkmcnt(0)" ::: "memory");
    SBAR;
    __builtin_amdgcn_s_barrier();
    SBAR;
    __builtin_amdgcn_s_setprio(1);
    MFMA16(4, afrY, bfrX);
    __builtin_amdgcn_s_setprio(0);
    SBAR;
    __builtin_amdgcn_s_barrier();
    SBAR;

    // ===== p2: MFMA(afrX,bfrY); prefetch afrY(cbuf k1 ih1); issue A(t2,ks0); write r1 =====
    #pragma unroll
    for (int ii = 0; ii < 4; ++ii)
      afrY[ii] = *(const bf16x8*)(cbuf + 8192 + aoff + (4 + ii) * 512);
    r2a = gload128(Asrc0 + t2 * 64);
    r2b = gload128(Asrc0 + t2 * 64 + rowstep);
    asm volatile("s_waitcnt vmcnt(2)" ::: "memory");
    ds_write128(nbuf + 16384 + 8192 + ldst0, r1a);           // B ks1 (tile t+1)
    ds_write128(nbuf + 16384 + 8192 + 4096 + ldst0, r1b);
    asm volatile("s_waitcnt lgkmcnt(0)" ::: "memory");
    SBAR;
    __builtin_amdgcn_s_barrier();
    SBAR;
    __builtin_amdgcn_s_setprio(1);
    MFMA16(0, afrX, bfrY);
    __builtin_amdgcn_s_setprio(0);
    SBAR;
    __builtin_amdgcn_s_barrier();
    SBAR;

    // ===== p3: MFMA(afrY,bfrY); prefetch bfrX,afrX(nbuf k0); issue B(t2,ks0); write r2 =====
    #pragma unroll
    for (int j = 0; j < 4; ++j)
      bfrX[j] = *(const bf16x8*)(nbuf + boff + j * 512);
    #pragma unroll
    for (int ii = 0; ii < 4; ++ii)
      afrX[ii] = *(const bf16x8*)(nbuf + aoff + ii * 512);
    r3a = gload128(Bsrc0 + t2 * 64);
    r3b = gload128(Bsrc0 + t2 * 64 + rowstep);
    asm volatile("s_waitcnt vmcnt(2)" ::: "memory");
    ds_write128(cbuf + ldst0, r2a);                          // A ks0 (tile t+2), region dead
    ds_write128(cbuf + 4096 + ldst0, r2b);
    asm volatile("s_waitcnt lgkmcnt(0)" ::: "memory");
    SBAR;
    __builtin_amdgcn_s_barrier();
    SBAR;
    __builtin_amdgcn_s_setprio(1);
    MFMA16(4, afrY, bfrY);
    __builtin_amdgcn_s_setprio(0);
    SBAR;
    __builtin_amdgcn_s_barrier();
    SBAR;
  }
  #undef MFMA16
  asm volatile("s_waitcnt vmcnt(0)" ::: "memory");    // drain dangling tail loads

  #pragma unroll
  for (int i = 0; i < 8; ++i) {
    const int grow0 = m0 + wm * 128 + i * 16 + (laneS << 2);
    #pragma unroll
    for (int j = 0; j < 4; ++j) {
      const int gcol = n0 + wn * 64 + j * 16 + laneR;
      #pragma unroll
      for (int r = 0; r < 4; ++r) {
        float v = acc[i][j][r];
        if (MODE == 0) {
          if (gcol < 1536) v = (v > 0.f) ? (v + 1.f) : __expf(v);   // phi on q,k
          reinterpret_cast<ushort*>(C)[(size_t)(grow0 + r) * N + gcol] = f2bf(v);
        } else {
          reinterpret_cast<float*>(C)[(size_t)(grow0 + r) * N + gcol] = v + bias[gcol];
        }
      }
    }
  }
}

// ==================== BMx256 2-phase GEMM (round-6; GEMM2, MFR=4) ========
template <int MODE, int MFR>
__global__ __launch_bounds__(512, 2) void gemm2ph(const ushort* __restrict__ A,
                                                  const ushort* __restrict__ Bt,
                                                  void* __restrict__ C,
                                                  const float* __restrict__ bias,
                                                  int N, int K, int nbx, int cpx) {
  constexpr int BM   = MFR * 32;
  constexpr int ALD  = MFR / 4;
  constexpr int AKS  = BM * 32;
  constexpr int BBASE = BM * 64;
  constexpr int BUFS = (BM + 256) * 64;
  extern __shared__ ushort lds[];
  const int tid = threadIdx.x;
  const int lane = tid & 63;
  const int wid = tid >> 6;
  const int wm = wid >> 2, wn = wid & 3;
  const int laneR = lane & 15, laneS = lane >> 4;

  const int bid = blockIdx.x;
  const int lin = (bid & 7) * cpx + (bid >> 3);
  const int by = lin / nbx, bx = lin - by * nbx;
  const int m0 = by * BM, n0 = bx * 256;
  const int NT = K >> 6;

  const int sr = tid >> 2, ss = tid & 3;
  const int sslot = ss ^ ((sr >> 1) & 3);
  const ushort* Asrc0 = A + (size_t)(m0 + sr) * K + sslot * 8;
  const ushort* Bsrc0 = Bt + (size_t)(n0 + sr) * K + sslot * 8;
  const size_t rowstep = (size_t)128 * K;
  const int ldst0 = tid * 8;

  const int sprime = laneS ^ ((laneR >> 1) & 3);
  const int aoff = (wm * (MFR * 16) + laneR) * 32 + sprime * 8;
  const int boff = BBASE + (wn * 64 + laneR) * 32 + sprime * 8;

  f32x4 acc[MFR][4] = {};
  bf16x8 afr[MFR], bfr[4];

  #define STAGE_K(KT, KS, DB)                                                     \
    { _Pragma("unroll")                                                           \
      for (int L = 0; L < ALD; ++L)                                               \
        gload_lds16(Asrc0 + (KT) * 64 + (KS) * 32 + (size_t)L * rowstep,          \
                    lds + (DB) + (KS) * AKS + L * 4096 + ldst0);                  \
      _Pragma("unroll")                                                           \
      for (int L = 0; L < 2; ++L)                                                 \
        gload_lds16(Bsrc0 + (KT) * 64 + (KS) * 32 + (size_t)L * rowstep,          \
                    lds + (DB) + BBASE + (KS) * 8192 + L * 4096 + ldst0); }
  #define VMCNT_WAIT                                                              \
    if constexpr (MFR == 8) asm volatile("s_waitcnt vmcnt(8)" ::: "memory");      \
    else                    asm volatile("s_waitcnt vmcnt(6)" ::: "memory");
  #define PHASE_SYNC                                                              \
    SBAR;                                                                         \
    __builtin_amdgcn_s_barrier();                                                 \
    asm volatile("s_waitcnt lgkmcnt(0)");                                         \
    SBAR;
  #define PHASE_END                                                               \
    SBAR;                                                                         \
    __builtin_amdgcn_s_barrier();                                                 \
    SBAR;
  #define MFMA_CL                                                                 \
    __builtin_amdgcn_s_setprio(1);                                                \
    _Pragma("unroll")                                                             \
    for (int ii = 0; ii < MFR; ++ii)                                              \
      _Pragma("unroll")                                                           \
      for (int j = 0; j < 4; ++j)                                                 \
        acc[ii][j] =                                                              \
            __builtin_amdgcn_mfma_f32_16x16x32_bf16(afr[ii], bfr[j], acc[ii][j], 0, 0, 0); \
    __builtin_amdgcn_s_setprio(0);

  STAGE_K(0, 0, 0);
  STAGE_K(0, 1, 0);
  STAGE_K(1, 0, BUFS);
  VMCNT_WAIT;
  SBAR;
  __builtin_amdgcn_s_barrier();
  SBAR;

  for (int t = 0; t < NT; ++t) {
    const int cb = (t & 1) * BUFS;
    const int nb = BUFS - cb;
    const int t1 = (t + 1 < NT) ? t + 1 : t;
    const int t2 = (t + 2 < NT) ? t + 2 : t;

    #pragma unroll
    for (int j = 0; j < 4; ++j) bfr[j] = ds_read128(lds + cb + boff + j * 512);
    #pragma unroll
    for (int ii = 0; ii < MFR; ++ii) afr[ii] = ds_read128(lds + cb + aoff + ii * 512);
    STAGE_K(t1, 1, nb);
    VMCNT_WAIT;
    PHASE_SYNC;
    MFMA_CL;
    PHASE_END;

    #pragma unroll
    for (int j = 0; j < 4; ++j) bfr[j] = ds_read128(lds + cb + 8192 + boff + j * 512);
    #pragma unroll
    for (int ii = 0; ii < MFR; ++ii) afr[ii] = ds_read128(lds + cb + AKS + aoff + ii * 512);
    STAGE_K(t2, 0, cb);
    VMCNT_WAIT;
    PHASE_SYNC;
    MFMA_CL;
    PHASE_END;
  }
  #undef STAGE_K
  #undef MFMA_CL
  #undef PHASE_SYNC
  #undef PHASE_END
  #undef VMCNT_WAIT
  asm volatile("s_waitcnt vmcnt(0)" ::: "memory");

  #pragma unroll
  for (int i = 0; i < MFR; ++i) {
    const int grow0 = m0 + wm * (MFR * 16) + i * 16 + (laneS << 2);
    #pragma unroll
    for (int j = 0; j < 4; ++j) {
      const int gcol = n0 + wn * 64 + j * 16 + laneR;
      #pragma unroll
      for (int r = 0; r < 4; ++r) {
        float v = acc[i][j][r];
        if (MODE == 0) {
          if (gcol < 1536) v = (v > 0.f) ? (v + 1.f) : __expf(v);
          reinterpret_cast<ushort*>(C)[(size_t)(grow0 + r) * N + gcol] = f2bf(v);
        } else {
          reinterpret_cast<float*>(C)[(size_t)(grow0 + r) * N + gcol] = v + bias[gcol];
        }
      }
    }
  }
}

// ---------------- kv partial: f32-in-LDS staging (convert once), stride-68 pad ------
__global__ __launch_bounds__(256) void kv_partial(const ushort* __restrict__ qkv,
                                                  float* __restrict__ kv_part,
                                                  float* __restrict__ ks_part) {
  const int blk = blockIdx.x;          // 384*4
  const int bh = blk >> 2, sp = blk & 3;
  const int b = bh / 12, h = bh % 12;
  const int tid = threadIdx.x;
  __shared__ float Ks[32 * 68];
  __shared__ float Vs[32 * 68];
  float acc[4][4] = {};                // [m][dq]
  float kacc[4] = {};
  const int dq0 = (tid & 15) * 4, mq0 = (tid >> 4) * 4;
  const int r = tid >> 3, o = (tid & 7) * 8;        // stage: row r, 8 cols from o
  for (int st = 0; st < 256; st += 32) {
    const size_t rowbase = (size_t)(b * 1024 + sp * 256 + st + r) * 2304 + h * 64 + o;
    int4 kraw = *reinterpret_cast<const int4*>(qkv + rowbase + 768);
    int4 vraw = *reinterpret_cast<const int4*>(qkv + rowbase + 1536);
    float kf[8], vf[8];
    {
      const unsigned* kw = reinterpret_cast<const unsigned*>(&kraw);
      const unsigned* vw = reinterpret_cast<const unsigned*>(&vraw);
      #pragma unroll
      for (int w = 0; w < 4; ++w) {
        kf[2 * w]     = bits2f(kw[w] << 16);
        kf[2 * w + 1] = bits2f(kw[w] & 0xffff0000u);
        vf[2 * w]     = bits2f(vw[w] << 16);
        vf[2 * w + 1] = bits2f(vw[w] & 0xffff0000u);
      }
    }
    __syncthreads();                   // prev-iter LDS reads done
    #pragma unroll
    for (int w = 0; w < 8; ++w) {
      Ks[r * 68 + o + w] = kf[w];
      Vs[r * 68 + o + w] = vf[w];
    }
    __syncthreads();                   // tile present
    #pragma unroll 8
    for (int s = 0; s < 32; ++s) {
      f32x4 kk = *reinterpret_cast<const f32x4*>(&Ks[s * 68 + dq0]);
      f32x4 vv = *reinterpret_cast<const f32x4*>(&Vs[s * 68 + mq0]);
      #pragma unroll
      for (int jm = 0; jm < 4; ++jm)
        #pragma unroll
        for (int id = 0; id < 4; ++id)
          acc[jm][id] += vv[jm] * kk[id];
      if (mq0 == 0) {
        #pragma unroll
        for (int id = 0; id < 4; ++id) kacc[id] += kk[id];
      }
    }
  }
  float* kvp = kv_part + ((size_t)sp * 384 + bh) * 4096;
  #pragma unroll
  for (int jm = 0; jm < 4; ++jm)
    #pragma unroll
    for (int id = 0; id < 4; ++id)
      kvp[(mq0 + jm) * 64 + dq0 + id] = acc[jm][id];
  if (mq0 == 0) {
    #pragma unroll
    for (int id = 0; id < 4; ++id)
      ks_part[((size_t)sp * 384 + bh) * 64 + dq0 + id] = kacc[id];
  }
}

// ---------------- reduce splits: kv -> bf16 [bh][m][dq], ksum += 1.0 (pad token) ----
__global__ __launch_bounds__(256) void kv_reduce(const float* __restrict__ kv_part,
                                                 const float* __restrict__ ks_part,
                                                 ushort* __restrict__ kv_bf,
                                                 float* __restrict__ ksum) {
  int i = blockIdx.x * 256 + threadIdx.x;
  if (i < 384 * 4096) {
    float s = 0.f;
    #pragma unroll
    for (int p = 0; p < 4; ++p) s += kv_part[(size_t)p * (384 * 4096) + i];
    kv_bf[i] = f2bf(s);
  }
  if (i < 384 * 64) {
    float s = 1.0f;    // phi(0)=1 contribution of the zero padding token
    #pragma unroll
    for (int p = 0; p < 4; ++p) s += ks_part[(size_t)p * (384 * 64) + i];
    ksum[i] = s;
  }
}

// ---------------- attention: out[t][h*64+m] = z[t] * sum_dq q[t][dq]*kv[dq][m] -------
__global__ __launch_bounds__(256) void attn_kernel(const ushort* __restrict__ qkv,
                                                   const ushort* __restrict__ kv_bf,
                                                   const float* __restrict__ ksum,
                                                   ushort* __restrict__ attn) {
  const int blk = blockIdx.x;          // 384*8
  const int bh = blk >> 3, tb = blk & 7;
  const int b = bh / 12, h = bh % 12;
  const int row0 = b * 1024 + tb * 128;
  __shared__ ushort Qs[128 * 64];
  __shared__ ushort KVs[64 * 64];      // [m][dq]
  __shared__ float zs[128];
  __shared__ float ks_lds[64];
  const int tid = threadIdx.x;
  const int lane = tid & 63, w = tid >> 6;
  #pragma unroll
  for (int j = 0; j < 4; ++j) {
    int c = j * 256 + tid;
    gload_lds16(qkv + (size_t)(row0 + (c >> 3)) * 2304 + h * 64 + (c & 7) * 8, &Qs[c * 8]);
  }
  #pragma unroll
  for (int j = 0; j < 2; ++j) {
    int c = j * 256 + tid;
    gload_lds16(kv_bf + (size_t)bh * 4096 + c * 8, &KVs[c * 8]);
  }
  if (tid < 64) ks_lds[tid] = ksum[bh * 64 + tid];
  asm volatile("s_waitcnt vmcnt(0)" ::: "memory");
  __syncthreads();
  if (tid < 128) {
    float d = 0.f;
    #pragma unroll 8
    for (int e = 0; e < 64; ++e) d += bf2f(Qs[tid * 64 + e]) * ks_lds[e];
    zs[tid] = 1.f / (d + 1e-6f);
  }
  __syncthreads();
  f32x4 acc[2][4] = {};
  #pragma unroll
  for (int ks = 0; ks < 2; ++ks) {
    bf16x8 a[2], bb[4];
    #pragma unroll
    for (int i = 0; i < 2; ++i)
      a[i] = *reinterpret_cast<const bf16x8*>(&Qs[(w * 32 + i * 16 + (lane & 15)) * 64 + ks * 32 + (lane >> 4) * 8]);
    #pragma unroll
    for (int j = 0; j < 4; ++j)
      bb[j] = *reinterpret_cast<const bf16x8*>(&KVs[(j * 16 + (lane & 15)) * 64 + ks * 32 + (lane >> 4) * 8]);
    #pragma unroll
    for (int i = 0; i < 2; ++i)
      #pragma unroll
      for (int j = 0; j < 4; ++j)
        acc[i][j] = __builtin_amdgcn_mfma_f32_16x16x32_bf16(a[i], bb[j], acc[i][j], 0, 0, 0);
  }
  #pragma unroll
  for (int i = 0; i < 2; ++i) {
    const int t0 = w * 32 + i * 16 + ((lane >> 4) << 2);
    #pragma unroll
    for (int j = 0; j < 4; ++j) {
      const int m = j * 16 + (lane & 15);
      #pragma unroll
      for (int r = 0; r < 4; ++r) {
        float v = acc[i][j][r] * zs[t0 + r];
        attn[(size_t)(row0 + t0 + r) * 768 + h * 64 + m] = f2bf(v);
      }
    }
  }
}

// ---------------- launch ----------------
extern "C" void kernel_launch(void* const* d_in, const int* in_sizes, int n_in,
                              void* d_out, int out_size, void* d_ws, size_t ws_size,
                              hipStream_t stream) {
  (void)in_sizes; (void)n_in; (void)out_size; (void)ws_size;
  const float* x    = (const float*)d_in[0];
  const float* Wqkv = (const float*)d_in[1];
  const float* Wout = (const float*)d_in[2];
  const float* bout = (const float*)d_in[3];
  float* out = (float*)d_out;
  char* ws = (char*)d_ws;

  // workspace layout (total ~210 MB); region 0 is reused by 3 time-disjoint buffers
  ushort* xbf    = (ushort*)(ws);               // 50,331,648 B : x bf16 [32768][768]
  ushort* wqkvT  = (ushort*)(ws + 50331648);    //  3,538,944 B : W_qkv^T bf16 [2304][768]
  ushort* woutT  = (ushort*)(ws + 53870592);    //  1,179,648 B : W_out^T bf16 [768][768]
  ushort* qkv    = (ushort*)(ws + 55050240);    // 150,994,944 B: phi(q)|phi(k)|v bf16 [32768][2304]
  float*  ksp    = (float*) (ws + 206045184);   //    393,216 B : ksum partials [4][384][64]
  ushort* kvbf   = (ushort*)(ws + 206438400);   //  3,145,728 B : kv bf16 [384][64m][64dq]
  float*  ksum   = (float*) (ws + 209584128);   //     98,304 B : ksum+1 [384][64]
  float*  kvpart = (float*)(ws);                // 25,165,824 B : overlays xbf (dead after gemm1)
  ushort* attn   = (ushort*)(ws);               // 50,331,648 B : overlays kvpart (dead after kv_reduce)

  static const int LDS1 = 131072;   // gemm256: 2 bufs x 64 KiB
  static const int LDS2 = 98304;    // gemm2ph MFR=4: (128+256)*64*2*2
  hipFuncSetAttribute(reinterpret_cast<const void*>(&gemm256<0>),
                      hipFuncAttributeMaxDynamicSharedMemorySize, LDS1);
  hipFuncSetAttribute(reinterpret_cast<const void*>(&gemm2ph<1, 4>),
                      hipFuncAttributeMaxDynamicSharedMemorySize, LDS2);

  cvt_f32_bf16<<<24576, 256, 0, stream>>>(x, xbf, 6291456);
  transpose_cvt<<<dim3(72, 24), 256, 0, stream>>>(Wqkv, wqkvT, 768, 2304);
  transpose_cvt<<<dim3(24, 24), 256, 0, stream>>>(Wout, woutT, 768, 768);
  // GEMM1: 256x256 tiles -> grid 128x9 = 1152 (cpx=144)
  gemm256<0><<<1152, 512, LDS1, stream>>>(xbf, wqkvT, qkv, nullptr, 2304, 768, 9, 144);
  kv_partial<<<1536, 256, 0, stream>>>(qkv, kvpart, ksp);
  kv_reduce<<<6144, 256, 0, stream>>>(kvpart, ksp, kvbf, ksum);
  attn_kernel<<<3072, 256, 0, stream>>>(qkv, kvbf, ksum, attn);
  // GEMM2: 128x256 tiles -> grid 256x3 = 768 (cpx=96), 3 exact generations
  gemm2ph<1, 4><<<768, 512, LDS2, stream>>>(attn, woutT, out, bout, 768, 768, 3, 96);
}

// Round 11
// 290.406 us; speedup vs baseline: 1.3711x; 1.0955x over previous
//
#include <hip/hip_runtime.h>
#include <hip/hip_bf16.h>

// B=32, N=1024, D=768, H=12, d=64. Real tokens M=32768.
// Pad token handled analytically: ksum += 1.0 per component, kv/output unaffected.

typedef __bf16 bf16x8 __attribute__((ext_vector_type(8)));
typedef float f32x4 __attribute__((ext_vector_type(4)));

__device__ __forceinline__ ushort f2bf(float f) {
  union { float f; unsigned u; } x; x.f = f;
  unsigned r = x.u + 0x7fffu + ((x.u >> 16) & 1u);   // RNE
  return (ushort)(r >> 16);
}
__device__ __forceinline__ float bf2f(ushort h) {
  union { unsigned u; float f; } x; x.u = ((unsigned)h) << 16;
  return x.f;
}
__device__ __forceinline__ float bits2f(unsigned u) {
  union { unsigned u; float f; } x; x.u = u;
  return x.f;
}
__device__ __forceinline__ void gload_lds16(const void* g, void* lds) {
  __builtin_amdgcn_global_load_lds((const __attribute__((address_space(1))) void*)g,
                                   (__attribute__((address_space(3))) void*)lds, 16, 0, 0);
}

// ---------------- fp32 -> bf16 elementwise (x4 vectorized) ----------------
__global__ __launch_bounds__(256) void cvt_f32_bf16(const float* __restrict__ in,
                                                    ushort* __restrict__ out, int n4) {
  int i = blockIdx.x * 256 + threadIdx.x;
  if (i >= n4) return;
  float4 v = reinterpret_cast<const float4*>(in)[i];
  ushort4 o;
  o.x = f2bf(v.x); o.y = f2bf(v.y); o.z = f2bf(v.z); o.w = f2bf(v.w);
  reinterpret_cast<ushort4*>(out)[i] = o;
}

// ---------------- transpose+convert: src[R][C] f32 -> dst[C][R] bf16 ----------------
__global__ __launch_bounds__(256) void transpose_cvt(const float* __restrict__ src,
                                                     ushort* __restrict__ dst, int R, int C) {
  __shared__ float tile[32][33];
  int bc = blockIdx.x * 32, br = blockIdx.y * 32;
  int tx = threadIdx.x & 31, ty = threadIdx.x >> 5;   // 32x8
  #pragma unroll
  for (int i = 0; i < 32; i += 8)
    tile[ty + i][tx] = src[(size_t)(br + ty + i) * C + (bc + tx)];
  __syncthreads();
  #pragma unroll
  for (int i = 0; i < 32; i += 8)
    dst[(size_t)(bc + ty + i) * R + (br + tx)] = f2bf(tile[tx][ty + i]);
}

// ==================== 128x256 triple-buffered 2-resident GEMM ====================
// C[M][N] = A[M][K] * Bt[N][K]^T, bf16 in, fp32 accum.
// 512 threads = 8 waves (2M x 4N), per-wave 64x64 out. BK=32, NT=K/32, 1 phase/tile.
// LDS = 3 bufs x 24 KB { A[128][32] | B[256][32] } = 72 KB -> 2 blocks/CU.
// Phase t: frag reads from buf[t%3] -> stage tile t+2 into buf[(t+2)%3] (3 loads:
// 1 A + 2 B per thread) -> vmcnt(3) (confirms tile t+1, never drains) -> barrier
// -> 16 MFMA -> barrier. Cross-block overlap (2 independent blocks/CU) hides the
// block-wide read/barrier serialization that capped all 1-block configs at
// ~1600 cy/phase (r2-r10 invariant).
// Hazards: buf[(t+2)%3] holds tile t-1, consumed at phase t-1; 2 barriers/phase
// bound wave skew so every wave has passed post-barrier(t-1) when the stage
// issues. XOR slot swizzle (conflict-free, PMC-verified 0).
// MODE 0: epilogue phi on cols<1536, store bf16.  MODE 1: +bias, store fp32.
template <int MODE>
__global__ __launch_bounds__(512, 4) void gemm3b(const ushort* __restrict__ A,
                                                 const ushort* __restrict__ Bt,
                                                 void* __restrict__ C,
                                                 const float* __restrict__ bias,
                                                 int N, int K, int nbx, int cpx) {
  extern __shared__ ushort lds[];
  const int tid = threadIdx.x;
  const int lane = tid & 63;
  const int wid = tid >> 6;
  const int wm = wid >> 2, wn = wid & 3;
  const int laneR = lane & 15, laneS = lane >> 4;

  // XCD-bijective swizzle (nwg % 8 == 0), bx-fastest within chunk
  const int bid = blockIdx.x;
  const int lin = (bid & 7) * cpx + (bid >> 3);
  const int by = lin / nbx, bx = lin - by * nbx;
  const int m0 = by * 128, n0 = bx * 256;
  const int NT = K >> 5;

  // staging: A 128x4 chunks (1/thread), B 256x4 chunks (2/thread, rows r and r+128)
  const int sr = tid >> 2, ss = tid & 3;
  const int sslot = ss ^ ((sr >> 1) & 3);              // same for sr and sr+128
  const ushort* Asrc = A + (size_t)(m0 + sr) * K + sslot * 8;
  const ushort* Bsrc = Bt + (size_t)(n0 + sr) * K + sslot * 8;
  const size_t rowstep128 = (size_t)128 * K;
  const int ldstA = tid * 8;                           // A region: 0..4095 ushorts
  const int ldstB = 4096 + tid * 8;                    // B region: 4096..12287

  // frag reads: swizzled slot per-lane constant (row ≡ laneR mod 8)
  const int sprime = laneS ^ ((laneR >> 1) & 3);
  const int aoff = (wm * 64 + laneR) * 32 + sprime * 8;        // + i*512
  const int boff = 4096 + (wn * 64 + laneR) * 32 + sprime * 8; // + j*512

  f32x4 acc[4][4] = {};

  #define SBAR  __builtin_amdgcn_sched_barrier(0)
  #define STAGE_T(KT, DB)                                                         \
    { gload_lds16(Asrc + (KT) * 32, lds + (DB) + ldstA);                          \
      gload_lds16(Bsrc + (KT) * 32, lds + (DB) + ldstB);                          \
      gload_lds16(Bsrc + (KT) * 32 + rowstep128, lds + (DB) + ldstB + 4096); }

  // ---- prologue: stage tiles 0,1; vmcnt(3) confirms tile 0 ----
  STAGE_T(0, 0);
  STAGE_T(1, 12288);
  asm volatile("s_waitcnt vmcnt(3)" ::: "memory");
  SBAR;
  __builtin_amdgcn_s_barrier();
  SBAR;

  for (int t = 0; t < NT; ++t) {
    const ushort* cb = lds + (t % 3) * 12288;
    const int db2 = ((t + 2) % 3) * 12288;
    const int t2 = (t + 2 < NT) ? t + 2 : t;   // clamped tail: dead dup stages
    bf16x8 a[4], b[4];
    #pragma unroll
    for (int j = 0; j < 4; ++j) b[j] = *(const bf16x8*)(cb + boff + j * 512);
    #pragma unroll
    for (int i = 0; i < 4; ++i) a[i] = *(const bf16x8*)(cb + aoff + i * 512);
    STAGE_T(t2, db2);
    asm volatile("s_waitcnt vmcnt(3)" ::: "memory");   // confirms tile t+1
    SBAR;
    __builtin_amdgcn_s_barrier();
    SBAR;
    __builtin_amdgcn_s_setprio(1);
    #pragma unroll
    for (int i = 0; i < 4; ++i)
      #pragma unroll
      for (int j = 0; j < 4; ++j)
        acc[i][j] = __builtin_amdgcn_mfma_f32_16x16x32_bf16(a[i], b[j], acc[i][j], 0, 0, 0);
    __builtin_amdgcn_s_setprio(0);
    SBAR;
    __builtin_amdgcn_s_barrier();
    SBAR;
  }
  #undef STAGE_T
  asm volatile("s_waitcnt vmcnt(0)" ::: "memory");     // drain dead tail stages

  // ---- epilogue: C/D layout col=lane&15, row=(lane>>4)*4+r ----
  #pragma unroll
  for (int i = 0; i < 4; ++i) {
    const int grow0 = m0 + wm * 64 + i * 16 + (laneS << 2);
    #pragma unroll
    for (int j = 0; j < 4; ++j) {
      const int gcol = n0 + wn * 64 + j * 16 + laneR;
      #pragma unroll
      for (int r = 0; r < 4; ++r) {
        float v = acc[i][j][r];
        if (MODE == 0) {
          if (gcol < 1536) v = (v > 0.f) ? (v + 1.f) : __expf(v);   // phi on q,k
          reinterpret_cast<ushort*>(C)[(size_t)(grow0 + r) * N + gcol] = f2bf(v);
        } else {
          reinterpret_cast<float*>(C)[(size_t)(grow0 + r) * N + gcol] = v + bias[gcol];
        }
      }
    }
  }
}

// ---------------- kv partial: f32-in-LDS staging (convert once), stride-68 pad ------
__global__ __launch_bounds__(256) void kv_partial(const ushort* __restrict__ qkv,
                                                  float* __restrict__ kv_part,
                                                  float* __restrict__ ks_part) {
  const int blk = blockIdx.x;          // 384*4
  const int bh = blk >> 2, sp = blk & 3;
  const int b = bh / 12, h = bh % 12;
  const int tid = threadIdx.x;
  __shared__ float Ks[32 * 68];
  __shared__ float Vs[32 * 68];
  float acc[4][4] = {};                // [m][dq]
  float kacc[4] = {};
  const int dq0 = (tid & 15) * 4, mq0 = (tid >> 4) * 4;
  const int r = tid >> 3, o = (tid & 7) * 8;        // stage: row r, 8 cols from o
  for (int st = 0; st < 256; st += 32) {
    const size_t rowbase = (size_t)(b * 1024 + sp * 256 + st + r) * 2304 + h * 64 + o;
    int4 kraw = *reinterpret_cast<const int4*>(qkv + rowbase + 768);
    int4 vraw = *reinterpret_cast<const int4*>(qkv + rowbase + 1536);
    float kf[8], vf[8];
    {
      const unsigned* kw = reinterpret_cast<const unsigned*>(&kraw);
      const unsigned* vw = reinterpret_cast<const unsigned*>(&vraw);
      #pragma unroll
      for (int w = 0; w < 4; ++w) {
        kf[2 * w]     = bits2f(kw[w] << 16);
        kf[2 * w + 1] = bits2f(kw[w] & 0xffff0000u);
        vf[2 * w]     = bits2f(vw[w] << 16);
        vf[2 * w + 1] = bits2f(vw[w] & 0xffff0000u);
      }
    }
    __syncthreads();                   // prev-iter LDS reads done
    #pragma unroll
    for (int w = 0; w < 8; ++w) {
      Ks[r * 68 + o + w] = kf[w];
      Vs[r * 68 + o + w] = vf[w];
    }
    __syncthreads();                   // tile present
    #pragma unroll 8
    for (int s = 0; s < 32; ++s) {
      f32x4 kk = *reinterpret_cast<const f32x4*>(&Ks[s * 68 + dq0]);
      f32x4 vv = *reinterpret_cast<const f32x4*>(&Vs[s * 68 + mq0]);
      #pragma unroll
      for (int jm = 0; jm < 4; ++jm)
        #pragma unroll
        for (int id = 0; id < 4; ++id)
          acc[jm][id] += vv[jm] * kk[id];
      if (mq0 == 0) {
        #pragma unroll
        for (int id = 0; id < 4; ++id) kacc[id] += kk[id];
      }
    }
  }
  float* kvp = kv_part + ((size_t)sp * 384 + bh) * 4096;
  #pragma unroll
  for (int jm = 0; jm < 4; ++jm)
    #pragma unroll
    for (int id = 0; id < 4; ++id)
      kvp[(mq0 + jm) * 64 + dq0 + id] = acc[jm][id];
  if (mq0 == 0) {
    #pragma unroll
    for (int id = 0; id < 4; ++id)
      ks_part[((size_t)sp * 384 + bh) * 64 + dq0 + id] = kacc[id];
  }
}

// ---------------- reduce splits: kv -> bf16 [bh][m][dq], ksum += 1.0 (pad token) ----
__global__ __launch_bounds__(256) void kv_reduce(const float* __restrict__ kv_part,
                                                 const float* __restrict__ ks_part,
                                                 ushort* __restrict__ kv_bf,
                                                 float* __restrict__ ksum) {
  int i = blockIdx.x * 256 + threadIdx.x;
  if (i < 384 * 4096) {
    float s = 0.f;
    #pragma unroll
    for (int p = 0; p < 4; ++p) s += kv_part[(size_t)p * (384 * 4096) + i];
    kv_bf[i] = f2bf(s);
  }
  if (i < 384 * 64) {
    float s = 1.0f;    // phi(0)=1 contribution of the zero padding token
    #pragma unroll
    for (int p = 0; p < 4; ++p) s += ks_part[(size_t)p * (384 * 64) + i];
    ksum[i] = s;
  }
}

// ---------------- attention: out[t][h*64+m] = z[t] * sum_dq q[t][dq]*kv[dq][m] -------
// LDS slot-XOR swizzle on Qs/KVs: row-stride 128B frag reads were 16-way
// bank-conflicted; staging pre-swizzles the SOURCE slot (gload_lds dest linear),
// reads XOR the slot -> <=2-way. z-dot vectorized (int4 LDS reads).
__global__ __launch_bounds__(256) void attn_kernel(const ushort* __restrict__ qkv,
                                                   const ushort* __restrict__ kv_bf,
                                                   const float* __restrict__ ksum,
                                                   ushort* __restrict__ attn) {
  const int blk = blockIdx.x;          // 384*8
  const int bh = blk >> 3, tb = blk & 7;
  const int b = bh / 12, h = bh % 12;
  const int row0 = b * 1024 + tb * 128;
  __shared__ ushort Qs[128 * 64];
  __shared__ ushort KVs[64 * 64];      // [m][dq]
  __shared__ float zs[128];
  __shared__ float ks_lds[64];
  const int tid = threadIdx.x;
  const int lane = tid & 63, w = tid >> 6;
  #pragma unroll
  for (int j = 0; j < 4; ++j) {
    int c = j * 256 + tid;
    int qr = c >> 3, dsl = c & 7;
    int ssl = dsl ^ (qr & 7);
    gload_lds16(qkv + (size_t)(row0 + qr) * 2304 + h * 64 + ssl * 8, &Qs[c * 8]);
  }
  #pragma unroll
  for (int j = 0; j < 2; ++j) {
    int c = j * 256 + tid;
    int mr = c >> 3, dsl = c & 7;
    int ssl = dsl ^ (mr & 7);
    gload_lds16(kv_bf + (size_t)bh * 4096 + mr * 64 + ssl * 8, &KVs[c * 8]);
  }
  if (tid < 64) ks_lds[tid] = ksum[bh * 64 + tid];
  asm volatile("s_waitcnt vmcnt(0)" ::: "memory");
  __syncthreads();
  if (tid < 128) {
    float d = 0.f;
    const int tx7 = tid & 7;
    #pragma unroll
    for (int s = 0; s < 8; ++s) {
      int4 raw = *reinterpret_cast<const int4*>(&Qs[tid * 64 + ((s ^ tx7) << 3)]);
      const unsigned* wds = reinterpret_cast<const unsigned*>(&raw);
      #pragma unroll
      for (int w2 = 0; w2 < 4; ++w2) {
        d += bits2f(wds[w2] << 16) * ks_lds[s * 8 + 2 * w2];
        d += bits2f(wds[w2] & 0xffff0000u) * ks_lds[s * 8 + 2 * w2 + 1];
      }
    }
    zs[tid] = 1.f / (d + 1e-6f);
  }
  __syncthreads();
  f32x4 acc[2][4] = {};
  const int lr7 = (lane & 15) & 7;
  #pragma unroll
  for (int ks = 0; ks < 2; ++ks) {
    const int sxor = ((ks * 4 + (lane >> 4)) ^ lr7) << 3;
    bf16x8 a[2], bb[4];
    #pragma unroll
    for (int i = 0; i < 2; ++i)
      a[i] = *reinterpret_cast<const bf16x8*>(&Qs[(w * 32 + i * 16 + (lane & 15)) * 64 + sxor]);
    #pragma unroll
    for (int j = 0; j < 4; ++j)
      bb[j] = *reinterpret_cast<const bf16x8*>(&KVs[(j * 16 + (lane & 15)) * 64 + sxor]);
    #pragma unroll
    for (int i = 0; i < 2; ++i)
      #pragma unroll
      for (int j = 0; j < 4; ++j)
        acc[i][j] = __builtin_amdgcn_mfma_f32_16x16x32_bf16(a[i], bb[j], acc[i][j], 0, 0, 0);
  }
  #pragma unroll
  for (int i = 0; i < 2; ++i) {
    const int t0 = w * 32 + i * 16 + ((lane >> 4) << 2);
    #pragma unroll
    for (int j = 0; j < 4; ++j) {
      const int m = j * 16 + (lane & 15);
      #pragma unroll
      for (int r = 0; r < 4; ++r) {
        float v = acc[i][j][r] * zs[t0 + r];
        attn[(size_t)(row0 + t0 + r) * 768 + h * 64 + m] = f2bf(v);
      }
    }
  }
}

// ---------------- launch ----------------
extern "C" void kernel_launch(void* const* d_in, const int* in_sizes, int n_in,
                              void* d_out, int out_size, void* d_ws, size_t ws_size,
                              hipStream_t stream) {
  (void)in_sizes; (void)n_in; (void)out_size; (void)ws_size;
  const float* x    = (const float*)d_in[0];
  const float* Wqkv = (const float*)d_in[1];
  const float* Wout = (const float*)d_in[2];
  const float* bout = (const float*)d_in[3];
  float* out = (float*)d_out;
  char* ws = (char*)d_ws;

  // workspace layout (total ~210 MB); region 0 is reused by 3 time-disjoint buffers
  ushort* xbf    = (ushort*)(ws);               // 50,331,648 B : x bf16 [32768][768]
  ushort* wqkvT  = (ushort*)(ws + 50331648);    //  3,538,944 B : W_qkv^T bf16 [2304][768]
  ushort* woutT  = (ushort*)(ws + 53870592);    //  1,179,648 B : W_out^T bf16 [768][768]
  ushort* qkv    = (ushort*)(ws + 55050240);    // 150,994,944 B: phi(q)|phi(k)|v bf16 [32768][2304]
  float*  ksp    = (float*) (ws + 206045184);   //    393,216 B : ksum partials [4][384][64]
  ushort* kvbf   = (ushort*)(ws + 206438400);   //  3,145,728 B : kv bf16 [384][64m][64dq]
  float*  ksum   = (float*) (ws + 209584128);   //     98,304 B : ksum+1 [384][64]
  float*  kvpart = (float*)(ws);                // 25,165,824 B : overlays xbf (dead after gemm1)
  ushort* attn   = (ushort*)(ws);               // 50,331,648 B : overlays kvpart (dead after kv_reduce)

  static const int LDS3 = 73728;    // gemm3b: 3 bufs x 24 KB
  hipFuncSetAttribute(reinterpret_cast<const void*>(&gemm3b<0>),
                      hipFuncAttributeMaxDynamicSharedMemorySize, LDS3);
  hipFuncSetAttribute(reinterpret_cast<const void*>(&gemm3b<1>),
                      hipFuncAttributeMaxDynamicSharedMemorySize, LDS3);

  cvt_f32_bf16<<<24576, 256, 0, stream>>>(x, xbf, 6291456);
  transpose_cvt<<<dim3(72, 24), 256, 0, stream>>>(Wqkv, wqkvT, 768, 2304);
  transpose_cvt<<<dim3(24, 24), 256, 0, stream>>>(Wout, woutT, 768, 768);
  // GEMM1: 128x256 tiles -> grid 256x9 = 2304 (cpx=288), 2 blocks/CU
  gemm3b<0><<<2304, 512, LDS3, stream>>>(xbf, wqkvT, qkv, nullptr, 2304, 768, 9, 288);
  kv_partial<<<1536, 256, 0, stream>>>(qkv, kvpart, ksp);
  kv_reduce<<<6144, 256, 0, stream>>>(kvpart, ksp, kvbf, ksum);
  attn_kernel<<<3072, 256, 0, stream>>>(qkv, kvbf, ksum, attn);
  // GEMM2: 128x256 tiles -> grid 256x3 = 768 (cpx=96)
  gemm3b<1><<<768, 512, LDS3, stream>>>(attn, woutT, out, bout, 768, 768, 3, 96);
}